// Round 8
// baseline (481.322 us; speedup 1.0000x reference)
//
#include <hip/hip_runtime.h>
#include <cstdint>
#include <cstddef>

typedef __attribute__((ext_vector_type(8))) short short8;
typedef __attribute__((ext_vector_type(4))) float f32x4;

#define DEV __device__ __forceinline__

DEV unsigned short f2bf(float f) {
  unsigned int u = __float_as_uint(f);
  u += 0x7fffu + ((u >> 16) & 1u);   // round-to-nearest-even
  return (unsigned short)(u >> 16);
}

DEV unsigned int pk2(float a, float b) {
  return (unsigned int)f2bf(a) | ((unsigned int)f2bf(b) << 16);
}

// async 16B global -> LDS (wave-uniform LDS base; HW adds lane*16)
DEV void glds16(const void* g, void* l) {
  __builtin_amdgcn_global_load_lds(
      (const __attribute__((address_space(1))) void*)g,
      (__attribute__((address_space(3))) void*)l, 16, 0, 0);
}

constexpr int NROW = 12288;

// ---------------- P0: t0T = (x @ W0)^T  -> bf16 [128][12288] ----------------
__global__ __launch_bounds__(256) void xw_kernel(
    const float* __restrict__ x, const float* __restrict__ W0,
    unsigned short* __restrict__ t0T) {
  __shared__ float sW[128 * 128];
  __shared__ float sx[16][128];
  const int t = threadIdx.x;
  for (int i = t; i < 128 * 128; i += 256) sW[i] = W0[i];
  const int r0 = blockIdx.x * 16;
  for (int i = t; i < 16 * 128; i += 256)
    sx[i >> 7][i & 127] = x[(size_t)(r0 + (i >> 7)) * 128 + (i & 127)];
  __syncthreads();
  const int c = t & 127;   // output column 0..127
  const int rg = t >> 7;   // row group: rows rg*8 .. rg*8+7
  float acc[8] = {0, 0, 0, 0, 0, 0, 0, 0};
  for (int k = 0; k < 128; ++k) {
    float w = sW[k * 128 + c];
#pragma unroll
    for (int j = 0; j < 8; ++j) acc[j] += sx[rg * 8 + j][k] * w;
  }
  uint4 o;
  o.x = pk2(acc[0], acc[1]);
  o.y = pk2(acc[2], acc[3]);
  o.z = pk2(acc[4], acc[5]);
  o.w = pk2(acc[6], acc[7]);
  *(uint4*)(t0T + (size_t)c * NROW + r0 + rg * 8) = o;
}

// ------------- big GEMM: part[split] = adj_chunk @ t   (bf16 MFMA) -----------
// A: [12288][12288] f32 (adj), BT: [H][12288] bf16 (t transposed)
// part: [KSPLIT][12288][H] f32
// Wave decomposition WM=4/WN=1: each wave owns 16 M-rows x all H cols, so
// A fragments are WAVE-PRIVATE -> A goes direct global->register (double-
// buffered named sets arA/arB, in-register f32->bf16 pack). LDS holds only
// B (DMA double-buffer, swizzle folded into the per-lane global source).
// ONE barrier per K-step, preceded by counted vmcnt(4).
// CRITICAL (R7 NaN fix): a sched_barrier(0) PINS the B-DMA cluster before
// the A register-prefetch cluster. vmcnt counts are only meaningful in
// static VMEM order; without the fence the scheduler may hoist A-loads
// above the DMAs and vmcnt(4) then leaves B-DMAs unretired at the barrier
// -> other waves read unwritten LDS.
template <int H>
__global__ __launch_bounds__(256, 3) void gcn_gemm(
    const float* __restrict__ A, const unsigned short* __restrict__ BT,
    float* __restrict__ part) {
  constexpr int KSPLIT = 4;
  constexpr int BM = 64, BK = 64;
  constexpr int NR = H / 16;                    // frags per wave (all cols)
  constexpr int NB = H / 32;                    // B DMA insts per thread/step
  constexpr int KSTEPS = (NROW / KSPLIT) / BK;  // 48 (even)
  constexpr int BBYTES = H * 128;               // one B^T tile (bf16)
  static_assert((KSTEPS & 1) == 0, "");

  __shared__ alignas(16) char ldsB[2 * BBYTES];

  const int t = threadIdx.x;
  // ---- split-per-XCD remap (grid = 768 = 8 XCD * 96) ----
  const int xcd = blockIdx.x & 7;
  const int idx = blockIdx.x >> 3;          // 0..95
  const int split = xcd >> 1;               // one split per XCD
  const int bm = ((xcd & 1) ? 96 : 0) + idx;
  const int k0 = split * (NROW / KSPLIT);

  const int wid = t >> 6, lane = t & 63;
  const int l15 = lane & 15, loct = lane >> 4;

  // ---- A direct-to-reg: lane covers row bm*64 + wid*16 + l15,
  //      cols k0 + s*64 + kk*32 + loct*8 (+0/+4) ----
  const float* aptr =
      A + (size_t)(bm * BM + wid * 16 + l15) * NROW + k0 + loct * 8;

  // ---- B^T staging source: swizzle folded into global address ----
  const int nB0 = t >> 3;                    // B row (+32 per chunk j)
  const int wB = (t & 7) ^ (nB0 & 7);        // pre-swizzled 16B chunk in row
  const unsigned short* bptr = BT + (size_t)nB0 * NROW + k0 + wB * 8;
  char* ldsBw = ldsB + wid * 1024;           // wave-uniform B DMA base

  // ---- B fragment LDS offsets (wn=0 for all waves) ----
  int boff[NR][2];
#pragma unroll
  for (int n = 0; n < NR; ++n)
#pragma unroll
    for (int kk = 0; kk < 2; ++kk) {
      int nn = n * 16 + l15;
      boff[n][kk] = (nn * 128 + kk * 64 + loct * 16) ^ ((nn & 7) << 4);
    }

  f32x4 acc[NR];
#pragma unroll
  for (int n = 0; n < NR; ++n) acc[n] = {0.f, 0.f, 0.f, 0.f};

  f32x4 arA[4], arB[4];   // A step regs: [kk*2+half], two named sets

  auto issueA = [&](f32x4* ar, int s) {
#pragma unroll
    for (int kk = 0; kk < 2; ++kk)
#pragma unroll
      for (int h = 0; h < 2; ++h)
        ar[kk * 2 + h] = *(const f32x4*)(aptr + s * BK + kk * 32 + h * 4);
  };
  auto glB = [&](int s, int buf) {
#pragma unroll
    for (int j = 0; j < NB; ++j)
      glds16(bptr + (size_t)j * 32 * NROW + s * BK,
             ldsBw + buf * BBYTES + j * 4096);
  };
  auto compute = [&](const f32x4* ar, int buf) {
    const char* lB = ldsB + buf * BBYTES;
#pragma unroll
    for (int kk = 0; kk < 2; ++kk) {
      union { unsigned int u[4]; short8 s8; } afu;
      afu.u[0] = pk2(ar[kk * 2].x, ar[kk * 2].y);
      afu.u[1] = pk2(ar[kk * 2].z, ar[kk * 2].w);
      afu.u[2] = pk2(ar[kk * 2 + 1].x, ar[kk * 2 + 1].y);
      afu.u[3] = pk2(ar[kk * 2 + 1].z, ar[kk * 2 + 1].w);
      const short8 af = afu.s8;
#pragma unroll
      for (int n = 0; n < NR; ++n) {
        const short8 bf = *(const short8*)(lB + boff[n][kk]);
        acc[n] = __builtin_amdgcn_mfma_f32_16x16x32_bf16(af, bf, acc[n],
                                                         0, 0, 0);
      }
    }
  };

  // ---- Prologue: B(0) DMA (pinned first); A(0),A(1); A(1) stays in flight --
  glB(0, 0);
  __builtin_amdgcn_sched_barrier(0);   // DMAs precede all A loads
  issueA(arA, 0);
  issueA(arB, 1);
  asm volatile("s_waitcnt vmcnt(4)" ::: "memory");  // B(0)+A(0) done
  __builtin_amdgcn_s_barrier();
  __builtin_amdgcn_sched_barrier(0);

  // ---- Main loop: steps 0..KSTEPS-3, pairwise (arA even, arB odd) ----
  for (int s = 0; s < KSTEPS - 2; s += 2) {
    // even step s (cur=arA, buf0): stage B(s+1)->buf1, A(s+2)->arA
    glB(s + 1, 1);
    __builtin_amdgcn_sched_barrier(0);   // pin: DMAs before A prefetch
    compute(arA, 0);
    issueA(arA, s + 2);
    asm volatile("s_waitcnt vmcnt(4) lgkmcnt(0)" ::: "memory");
    __builtin_amdgcn_s_barrier();
    __builtin_amdgcn_sched_barrier(0);
    // odd step s+1 (cur=arB, buf1): stage B(s+2)->buf0, A(s+3)->arB
    glB(s + 2, 0);
    __builtin_amdgcn_sched_barrier(0);   // pin: DMAs before A prefetch
    compute(arB, 1);
    issueA(arB, s + 3);
    asm volatile("s_waitcnt vmcnt(4) lgkmcnt(0)" ::: "memory");
    __builtin_amdgcn_s_barrier();
    __builtin_amdgcn_sched_barrier(0);
  }

  // ---- Peeled tail: steps KSTEPS-2 (arA, buf0), KSTEPS-1 (arB, buf1) ----
  glB(KSTEPS - 1, 1);
  __builtin_amdgcn_sched_barrier(0);
  compute(arA, 0);
  asm volatile("s_waitcnt vmcnt(0) lgkmcnt(0)" ::: "memory");
  __builtin_amdgcn_s_barrier();
  __builtin_amdgcn_sched_barrier(0);
  compute(arB, 1);

  // ---- Epilogue: C/D frag (col=l15, row=loct*4+rr) ----
  float* pout = part + ((size_t)split * NROW + (size_t)bm * BM + wid * 16) * H;
#pragma unroll
  for (int n = 0; n < NR; ++n)
#pragma unroll
    for (int rr = 0; rr < 4; ++rr)
      pout[(size_t)(loct * 4 + rr) * H + n * 16 + l15] = acc[n][rr];
}

// ------- reduce: sum splits + bias + LN + (leaky) + @Wnext -> t_next^T -------
template <int H, int H2, bool ACT>
__global__ __launch_bounds__(256) void reduce_ln(
    const float* __restrict__ part, const float* __restrict__ bias,
    const float* __restrict__ g, const float* __restrict__ be,
    const float* __restrict__ Wn, unsigned short* __restrict__ tT) {
  __shared__ float sW[H * H2];
  __shared__ float sh[4][H];
  const int t = threadIdx.x;
  for (int i = t; i < H * H2; i += 256) sW[i] = Wn[i];
  __syncthreads();

  const int wid = t >> 6, lane = t & 63;
  const int row = blockIdx.x * 4 + wid;
  constexpr int CPL = H / 64;
  float v[CPL];
#pragma unroll
  for (int c = 0; c < CPL; ++c) {
    const int col = lane + c * 64;
    float s = bias[col];
#pragma unroll
    for (int sp = 0; sp < 4; ++sp)
      s += part[((size_t)sp * NROW + row) * H + col];
    v[c] = s;
  }
  float sum = 0;
#pragma unroll
  for (int c = 0; c < CPL; ++c) sum += v[c];
#pragma unroll
  for (int o = 32; o > 0; o >>= 1) sum += __shfl_xor(sum, o);
  const float mu = sum / H;
  float vs = 0;
#pragma unroll
  for (int c = 0; c < CPL; ++c) { float d = v[c] - mu; vs += d * d; }
#pragma unroll
  for (int o = 32; o > 0; o >>= 1) vs += __shfl_xor(vs, o);
  const float rstd = rsqrtf(vs / H + 1e-5f);
#pragma unroll
  for (int c = 0; c < CPL; ++c) {
    const int col = lane + c * 64;
    float h = (v[c] - mu) * rstd * g[col] + be[col];
    if (ACT) h = (h > 0.f) ? h : 0.01f * h;
    sh[wid][col] = h;
  }
  __syncthreads();
  if (lane < H2) {
    float d = 0;
#pragma unroll 8
    for (int k = 0; k < H; ++k) d += sh[wid][k] * sW[k * H2 + lane];
    tT[(size_t)lane * NROW + row] = f2bf(d);
  }
}

// ------- final: sum splits + bias + LN + leaky + @Wl+bl + log_softmax -------
__global__ __launch_bounds__(256) void reduce_final(
    const float* __restrict__ part, const float* __restrict__ bias,
    const float* __restrict__ g, const float* __restrict__ be,
    const float* __restrict__ Wl, const float* __restrict__ bl,
    float* __restrict__ out) {
  __shared__ float sW[32 * 20];
  __shared__ float sbl[20];
  __shared__ float sh[4][32];
  __shared__ float sl[4][20];
  const int t = threadIdx.x;
  for (int i = t; i < 640; i += 256) sW[i] = Wl[i];
  if (t < 20) sbl[t] = bl[t];
  __syncthreads();
  const int wid = t >> 6, lane = t & 63;
  const int row = blockIdx.x * 4 + wid;
  const int col = lane & 31;  // lanes 32..63 duplicate cols 0..31
  float v = bias[col];
#pragma unroll
  for (int sp = 0; sp < 4; ++sp)
    v += part[((size_t)sp * NROW + row) * 32 + col];
  float sum = v;
#pragma unroll
  for (int o = 32; o > 0; o >>= 1) sum += __shfl_xor(sum, o);
  const float mu = sum / 64.f;  // values duplicated 2x across the wave
  float d0 = v - mu;
  float vs = d0 * d0;
#pragma unroll
  for (int o = 32; o > 0; o >>= 1) vs += __shfl_xor(vs, o);
  const float rstd = rsqrtf(vs / 64.f + 1e-5f);
  float h = (v - mu) * rstd * g[col] + be[col];
  h = (h > 0.f) ? h : 0.01f * h;
  if (lane < 32) sh[wid][col] = h;
  __syncthreads();
  if (lane < 20) {
    float lg = sbl[lane];
#pragma unroll
    for (int k = 0; k < 32; ++k) lg += sh[wid][k] * sW[k * 20 + lane];
    sl[wid][lane] = lg;
  }
  __syncthreads();
  if (lane < 20) {
    float mx = -1e30f;
#pragma unroll
    for (int k = 0; k < 20; ++k) mx = fmaxf(mx, sl[wid][k]);
    float se = 0.f;
#pragma unroll
    for (int k = 0; k < 20; ++k) se += expf(sl[wid][k] - mx);
    out[(size_t)row * 20 + lane] = sl[wid][lane] - mx - logf(se);
  }
}

extern "C" void kernel_launch(void* const* d_in, const int* in_sizes, int n_in,
                              void* d_out, int out_size, void* d_ws,
                              size_t ws_size, hipStream_t stream) {
  const float* x    = (const float*)d_in[0];
  const float* adj0 = (const float*)d_in[1];
  const float* adj1 = (const float*)d_in[2];
  const float* adj2 = (const float*)d_in[3];
  const float* W0   = (const float*)d_in[4];
  const float* b0   = (const float*)d_in[5];
  const float* W1   = (const float*)d_in[6];
  const float* b1   = (const float*)d_in[7];
  const float* W2   = (const float*)d_in[8];
  const float* b2   = (const float*)d_in[9];
  const float* g0   = (const float*)d_in[10];
  const float* be0  = (const float*)d_in[11];
  const float* g1   = (const float*)d_in[12];
  const float* be1  = (const float*)d_in[13];
  const float* g2   = (const float*)d_in[14];
  const float* be2  = (const float*)d_in[15];
  const float* Wl   = (const float*)d_in[16];
  const float* bl   = (const float*)d_in[17];
  float* out = (float*)d_out;

  char* ws = (char*)d_ws;
  float* part =          (float*)(ws);                      // 4*12288*128*4 = 25165824 B
  unsigned short* t0T = (unsigned short*)(ws + 25165824);   // 128*12288*2 = 3145728 B
  unsigned short* t1T = (unsigned short*)(ws + 25165824 + 3145728);          // 1572864 B
  unsigned short* t2T = (unsigned short*)(ws + 25165824 + 3145728 + 1572864); // 786432 B

  xw_kernel<<<NROW / 16, 256, 0, stream>>>(x, W0, t0T);
  gcn_gemm<128><<<(NROW / 64) * 4, 256, 0, stream>>>(adj0, t0T, part);
  reduce_ln<128, 64, false><<<NROW / 4, 256, 0, stream>>>(part, b0, g0, be0, W1, t1T);
  gcn_gemm<64><<<(NROW / 64) * 4, 256, 0, stream>>>(adj1, t1T, part);
  reduce_ln<64, 32, true><<<NROW / 4, 256, 0, stream>>>(part, b1, g1, be1, W2, t2T);
  gcn_gemm<32><<<(NROW / 64) * 4, 256, 0, stream>>>(adj2, t2T, part);
  reduce_final<<<NROW / 4, 256, 0, stream>>>(part, b2, g2, be2, Wl, bl, out);
}

// Round 9
// 468.077 us; speedup vs baseline: 1.0283x; 1.0283x over previous
//
#include <hip/hip_runtime.h>
#include <cstdint>
#include <cstddef>

typedef __attribute__((ext_vector_type(8))) short short8;
typedef __attribute__((ext_vector_type(4))) float f32x4;

#define DEV __device__ __forceinline__

DEV unsigned short f2bf(float f) {
  unsigned int u = __float_as_uint(f);
  u += 0x7fffu + ((u >> 16) & 1u);   // round-to-nearest-even
  return (unsigned short)(u >> 16);
}

DEV unsigned int pk2(float a, float b) {
  return (unsigned int)f2bf(a) | ((unsigned int)f2bf(b) << 16);
}

// async 16B global -> LDS (wave-uniform LDS base; HW adds lane*16)
DEV void glds16(const void* g, void* l) {
  __builtin_amdgcn_global_load_lds(
      (const __attribute__((address_space(1))) void*)g,
      (__attribute__((address_space(3))) void*)l, 16, 0, 0);
}

constexpr int NROW = 12288;

// ---------------- P0: t0T = (x @ W0)^T  -> bf16 [128][12288] ----------------
__global__ __launch_bounds__(256) void xw_kernel(
    const float* __restrict__ x, const float* __restrict__ W0,
    unsigned short* __restrict__ t0T) {
  __shared__ float sW[128 * 128];
  __shared__ float sx[16][128];
  const int t = threadIdx.x;
  for (int i = t; i < 128 * 128; i += 256) sW[i] = W0[i];
  const int r0 = blockIdx.x * 16;
  for (int i = t; i < 16 * 128; i += 256)
    sx[i >> 7][i & 127] = x[(size_t)(r0 + (i >> 7)) * 128 + (i & 127)];
  __syncthreads();
  const int c = t & 127;   // output column 0..127
  const int rg = t >> 7;   // row group: rows rg*8 .. rg*8+7
  float acc[8] = {0, 0, 0, 0, 0, 0, 0, 0};
  for (int k = 0; k < 128; ++k) {
    float w = sW[k * 128 + c];
#pragma unroll
    for (int j = 0; j < 8; ++j) acc[j] += sx[rg * 8 + j][k] * w;
  }
  uint4 o;
  o.x = pk2(acc[0], acc[1]);
  o.y = pk2(acc[2], acc[3]);
  o.z = pk2(acc[4], acc[5]);
  o.w = pk2(acc[6], acc[7]);
  *(uint4*)(t0T + (size_t)c * NROW + r0 + rg * 8) = o;
}

// ------------- big GEMM: part[split] = adj_chunk @ t   (bf16 MFMA) -----------
// A: [12288][12288] f32 (adj), BT: [H][12288] bf16 (t^T)
// part: [2][12288][H] f32
// Geometry: BM=32, KSPLIT=2 (grid 768 = 3/CU). Superstep = 6 K-steps: each
// thread owns 8 f32/step of one row (8 threads/row) -> issueSuper reads
// 12 f32x4 covering 1536B CONTIGUOUS per row (2x R6's burst) at the same
// 48-VGPR budget. Slices dribbled into the A double-buffer one step ahead.
// Schedule = R6 skeleton: one raw s_barrier per K-step; vmcnt(12) only at
// the superstep-issue step (j=4, after slice5 frees the av set); vmcnt(0)
// elsewhere. R8's sched_barrier(0) pin between B-DMA cluster and A-load
// cluster kept (vmcnt counts require static VMEM order).
template <int H>
__global__ __launch_bounds__(256, 3) void gcn_gemm(
    const float* __restrict__ A, const unsigned short* __restrict__ BT,
    float* __restrict__ part) {
  constexpr int BM = 32, BK = 64;
  constexpr int NR = H / 32;                    // frags per wave (WN=2)
  constexpr int NB = H / 32;                    // B DMA rounds per thread/step
  constexpr int KHALF = NROW / 2;               // 6144
  constexpr int KSTEPS = KHALF / BK;            // 96
  constexpr int NSUP = KSTEPS / 6;              // 16
  constexpr int BBYTES = H * 128;               // one B tile (H x 64 bf16)

  __shared__ alignas(16) char ldsA[2 * 4096];   // [32][128B] x2
  __shared__ alignas(16) char ldsB[2 * BBYTES];

  const int t = threadIdx.x;
  // ---- split-per-XCD remap (grid = 768 = 8 XCD * 96; 4 XCDs per split) ----
  const int xcd = blockIdx.x & 7;
  const int idx = blockIdx.x >> 3;              // 0..95
  const int split = xcd >> 2;                   // 0..1
  const int bm = (xcd & 3) * 96 + idx;          // 0..383
  const int k0 = split * KHALF;

  // ---- A staging: 8 threads/row; thread (r=t>>3, q=t&7) reads 8 f32/step,
  //      6 steps/superstep: per-row burst = 1536B contiguous ----
  const int r = t >> 3, q = t & 7;
  const float* aptr = A + (size_t)(bm * BM + r) * NROW + k0 + q * 8;
  const int aw = (r * 128 + q * 16) ^ ((r & 7) << 4);  // swizzled byte off

  // ---- B staging source: swizzle folded into global address ----
  const int nB0 = t >> 3;                       // B row (+32 per round)
  const int wB = (t & 7) ^ (nB0 & 7);           // pre-swizzled 16B chunk
  const unsigned short* bptr = BT + (size_t)nB0 * NROW + k0 + wB * 8;
  const int wid = t >> 6;
  char* ldsBw = ldsB + wid * 1024;              // wave-uniform B DMA base

  // ---- MFMA fragment offsets (WM=2, WN=2) ----
  const int lane = t & 63;
  const int l15 = lane & 15, loct = lane >> 4;
  const int wm = wid >> 1, wn = wid & 1;
  int aoff[2], boff[NR][2];
#pragma unroll
  for (int kk = 0; kk < 2; ++kk) {
    const int row = wm * 16 + l15;
    aoff[kk] = (row * 128 + kk * 64 + loct * 16) ^ ((row & 7) << 4);
  }
#pragma unroll
  for (int n = 0; n < NR; ++n)
#pragma unroll
    for (int kk = 0; kk < 2; ++kk) {
      const int nn = wn * (NR * 16) + n * 16 + l15;
      boff[n][kk] = (nn * 128 + kk * 64 + loct * 16) ^ ((nn & 7) << 4);
    }

  f32x4 acc[NR];
#pragma unroll
  for (int n = 0; n < NR; ++n) acc[n] = {0.f, 0.f, 0.f, 0.f};

  f32x4 av[12];   // one superstep's A (48 VGPR); av[2j],av[2j+1] = slice j

  auto issueSuper = [&](int S) {
#pragma unroll
    for (int j = 0; j < 6; ++j) {
      av[2 * j]     = *(const f32x4*)(aptr + S * 384 + j * 64);
      av[2 * j + 1] = *(const f32x4*)(aptr + S * 384 + j * 64 + 4);
    }
  };
  auto glB = [&](int s, int buf) {
#pragma unroll
    for (int j = 0; j < NB; ++j)
      glds16(bptr + (size_t)j * 32 * NROW + s * BK,
             ldsBw + buf * BBYTES + j * 4096);
  };
  auto cvtWrite = [&](int j, int buf) {   // write slice j into A buf
    uint4 w;
    w.x = pk2(av[2 * j].x, av[2 * j].y);
    w.y = pk2(av[2 * j].z, av[2 * j].w);
    w.z = pk2(av[2 * j + 1].x, av[2 * j + 1].y);
    w.w = pk2(av[2 * j + 1].z, av[2 * j + 1].w);
    *(uint4*)(ldsA + buf * 4096 + aw) = w;
  };
  auto compute = [&](int buf) {
    const char* lA = ldsA + buf * 4096;
    const char* lB = ldsB + buf * BBYTES;
#pragma unroll
    for (int kk = 0; kk < 2; ++kk) {
      const short8 af = *(const short8*)(lA + aoff[kk]);
#pragma unroll
      for (int n = 0; n < NR; ++n) {
        const short8 bf = *(const short8*)(lB + boff[n][kk]);
        acc[n] = __builtin_amdgcn_mfma_f32_16x16x32_bf16(af, bf, acc[n],
                                                         0, 0, 0);
      }
    }
  };

#define WAITBAR(vmstr)                                        \
  asm volatile("s_waitcnt " vmstr " lgkmcnt(0)" ::: "memory"); \
  __builtin_amdgcn_s_barrier();                                \
  __builtin_amdgcn_sched_barrier(0);

  // ---- Prologue: B(0) DMA (pinned first); superstep0 burst; slice0 ----
  glB(0, 0);
  __builtin_amdgcn_sched_barrier(0);   // pin: DMAs precede A loads
  issueSuper(0);
  asm volatile("s_waitcnt vmcnt(12)" ::: "memory");  // retire B(0)
  cvtWrite(0, 0);                      // auto-waits av[0..1]
  WAITBAR("vmcnt(12)");                // A tail may remain in flight

  // ---- Main loop: supersteps 0..NSUP-2 (steps s=6S+j, buf=j&1) ----
  for (int S = 0; S < NSUP - 1; ++S) {
    const int s = 6 * S;
    // j=0
    glB(s + 1, 1);
    compute(0);
    cvtWrite(1, 1);
    WAITBAR("vmcnt(0)");
    // j=1
    glB(s + 2, 0);
    compute(1);
    cvtWrite(2, 0);
    WAITBAR("vmcnt(0)");
    // j=2
    glB(s + 3, 1);
    compute(0);
    cvtWrite(3, 1);
    WAITBAR("vmcnt(0)");
    // j=3
    glB(s + 4, 0);
    compute(1);
    cvtWrite(4, 0);
    WAITBAR("vmcnt(0)");
    // j=4: last slice of this set, then burst-issue next set
    glB(s + 5, 1);
    __builtin_amdgcn_sched_barrier(0);   // pin: DMAs before A loads
    compute(0);
    cvtWrite(5, 1);                      // frees av
    issueSuper(S + 1);                   // 12 loads, in flight across barrier
    WAITBAR("vmcnt(12)");
    // j=5: stage slice0 of NEW set (arrived ~1 step later)
    glB(s + 6, 0);
    compute(1);
    cvtWrite(0, 0);                      // auto-waits av[0..1]
    WAITBAR("vmcnt(0)");
  }

  // ---- Tail superstep S=NSUP-1 (steps 90..95, no further prefetch) ----
  {
    const int s = 6 * (NSUP - 1);
    glB(s + 1, 1); compute(0); cvtWrite(1, 1); WAITBAR("vmcnt(0)");
    glB(s + 2, 0); compute(1); cvtWrite(2, 0); WAITBAR("vmcnt(0)");
    glB(s + 3, 1); compute(0); cvtWrite(3, 1); WAITBAR("vmcnt(0)");
    glB(s + 4, 0); compute(1); cvtWrite(4, 0); WAITBAR("vmcnt(0)");
    glB(s + 5, 1); compute(0); cvtWrite(5, 1); WAITBAR("vmcnt(0)");
    compute(1);                          // final step
  }
#undef WAITBAR

  // ---- Epilogue: C/D frag (col=l15, row=loct*4+rr) ----
  float* pout =
      part + ((size_t)split * NROW + (size_t)bm * BM + wm * 16) * H;
#pragma unroll
  for (int n = 0; n < NR; ++n)
#pragma unroll
    for (int rr = 0; rr < 4; ++rr)
      pout[(size_t)(loct * 4 + rr) * H + wn * (NR * 16) + n * 16 + l15] =
          acc[n][rr];
}

// ------- reduce: sum splits + bias + LN + (leaky) + @Wnext -> t_next^T -------
template <int H, int H2, bool ACT>
__global__ __launch_bounds__(256) void reduce_ln(
    const float* __restrict__ part, const float* __restrict__ bias,
    const float* __restrict__ g, const float* __restrict__ be,
    const float* __restrict__ Wn, unsigned short* __restrict__ tT) {
  __shared__ float sW[H * H2];
  __shared__ float sh[4][H];
  const int t = threadIdx.x;
  for (int i = t; i < H * H2; i += 256) sW[i] = Wn[i];
  __syncthreads();

  const int wid = t >> 6, lane = t & 63;
  const int row = blockIdx.x * 4 + wid;
  constexpr int CPL = H / 64;
  float v[CPL];
#pragma unroll
  for (int c = 0; c < CPL; ++c) {
    const int col = lane + c * 64;
    float s = bias[col];
#pragma unroll
    for (int sp = 0; sp < 2; ++sp)
      s += part[((size_t)sp * NROW + row) * H + col];
    v[c] = s;
  }
  float sum = 0;
#pragma unroll
  for (int c = 0; c < CPL; ++c) sum += v[c];
#pragma unroll
  for (int o = 32; o > 0; o >>= 1) sum += __shfl_xor(sum, o);
  const float mu = sum / H;
  float vs = 0;
#pragma unroll
  for (int c = 0; c < CPL; ++c) { float d = v[c] - mu; vs += d * d; }
#pragma unroll
  for (int o = 32; o > 0; o >>= 1) vs += __shfl_xor(vs, o);
  const float rstd = rsqrtf(vs / H + 1e-5f);
#pragma unroll
  for (int c = 0; c < CPL; ++c) {
    const int col = lane + c * 64;
    float h = (v[c] - mu) * rstd * g[col] + be[col];
    if (ACT) h = (h > 0.f) ? h : 0.01f * h;
    sh[wid][col] = h;
  }
  __syncthreads();
  if (lane < H2) {
    float d = 0;
#pragma unroll 8
    for (int k = 0; k < H; ++k) d += sh[wid][k] * sW[k * H2 + lane];
    tT[(size_t)lane * NROW + row] = f2bf(d);
  }
}

// ------- final: sum splits + bias + LN + leaky + @Wl+bl + log_softmax -------
__global__ __launch_bounds__(256) void reduce_final(
    const float* __restrict__ part, const float* __restrict__ bias,
    const float* __restrict__ g, const float* __restrict__ be,
    const float* __restrict__ Wl, const float* __restrict__ bl,
    float* __restrict__ out) {
  __shared__ float sW[32 * 20];
  __shared__ float sbl[20];
  __shared__ float sh[4][32];
  __shared__ float sl[4][20];
  const int t = threadIdx.x;
  for (int i = t; i < 640; i += 256) sW[i] = Wl[i];
  if (t < 20) sbl[t] = bl[t];
  __syncthreads();
  const int wid = t >> 6, lane = t & 63;
  const int row = blockIdx.x * 4 + wid;
  const int col = lane & 31;  // lanes 32..63 duplicate cols 0..31
  float v = bias[col];
#pragma unroll
  for (int sp = 0; sp < 2; ++sp)
    v += part[((size_t)sp * NROW + row) * 32 + col];
  float sum = v;
#pragma unroll
  for (int o = 32; o > 0; o >>= 1) sum += __shfl_xor(sum, o);
  const float mu = sum / 64.f;  // values duplicated 2x across the wave
  float d0 = v - mu;
  float vs = d0 * d0;
#pragma unroll
  for (int o = 32; o > 0; o >>= 1) vs += __shfl_xor(vs, o);
  const float rstd = rsqrtf(vs / 64.f + 1e-5f);
  float h = (v - mu) * rstd * g[col] + be[col];
  h = (h > 0.f) ? h : 0.01f * h;
  if (lane < 32) sh[wid][col] = h;
  __syncthreads();
  if (lane < 20) {
    float lg = sbl[lane];
#pragma unroll
    for (int k = 0; k < 32; ++k) lg += sh[wid][k] * sW[k * 20 + lane];
    sl[wid][lane] = lg;
  }
  __syncthreads();
  if (lane < 20) {
    float mx = -1e30f;
#pragma unroll
    for (int k = 0; k < 20; ++k) mx = fmaxf(mx, sl[wid][k]);
    float se = 0.f;
#pragma unroll
    for (int k = 0; k < 20; ++k) se += expf(sl[wid][k] - mx);
    out[(size_t)row * 20 + lane] = sl[wid][lane] - mx - logf(se);
  }
}

extern "C" void kernel_launch(void* const* d_in, const int* in_sizes, int n_in,
                              void* d_out, int out_size, void* d_ws,
                              size_t ws_size, hipStream_t stream) {
  const float* x    = (const float*)d_in[0];
  const float* adj0 = (const float*)d_in[1];
  const float* adj1 = (const float*)d_in[2];
  const float* adj2 = (const float*)d_in[3];
  const float* W0   = (const float*)d_in[4];
  const float* b0   = (const float*)d_in[5];
  const float* W1   = (const float*)d_in[6];
  const float* b1   = (const float*)d_in[7];
  const float* W2   = (const float*)d_in[8];
  const float* b2   = (const float*)d_in[9];
  const float* g0   = (const float*)d_in[10];
  const float* be0  = (const float*)d_in[11];
  const float* g1   = (const float*)d_in[12];
  const float* be1  = (const float*)d_in[13];
  const float* g2   = (const float*)d_in[14];
  const float* be2  = (const float*)d_in[15];
  const float* Wl   = (const float*)d_in[16];
  const float* bl   = (const float*)d_in[17];
  float* out = (float*)d_out;

  char* ws = (char*)d_ws;
  float* part =          (float*)(ws);                      // 2*12288*128*4 = 12582912 B
  unsigned short* t0T = (unsigned short*)(ws + 25165824);   // 128*12288*2 = 3145728 B
  unsigned short* t1T = (unsigned short*)(ws + 25165824 + 3145728);          // 1572864 B
  unsigned short* t2T = (unsigned short*)(ws + 25165824 + 3145728 + 1572864); // 786432 B

  xw_kernel<<<NROW / 16, 256, 0, stream>>>(x, W0, t0T);
  gcn_gemm<128><<<768, 256, 0, stream>>>(adj0, t0T, part);
  reduce_ln<128, 64, false><<<NROW / 4, 256, 0, stream>>>(part, b0, g0, be0, W1, t1T);
  gcn_gemm<64><<<768, 256, 0, stream>>>(adj1, t1T, part);
  reduce_ln<64, 32, true><<<NROW / 4, 256, 0, stream>>>(part, b1, g1, be1, W2, t2T);
  gcn_gemm<32><<<768, 256, 0, stream>>>(adj2, t2T, part);
  reduce_final<<<NROW / 4, 256, 0, stream>>>(part, b2, g2, be2, Wl, bl, out);
}

// Round 10
// 449.198 us; speedup vs baseline: 1.0715x; 1.0420x over previous
//
#include <hip/hip_runtime.h>
#include <cstdint>
#include <cstddef>

typedef __attribute__((ext_vector_type(8))) short short8;
typedef __attribute__((ext_vector_type(4))) float f32x4;

#define DEV __device__ __forceinline__

DEV unsigned short f2bf(float f) {
  unsigned int u = __float_as_uint(f);
  u += 0x7fffu + ((u >> 16) & 1u);   // round-to-nearest-even
  return (unsigned short)(u >> 16);
}

DEV unsigned int pk2(float a, float b) {
  return (unsigned int)f2bf(a) | ((unsigned int)f2bf(b) << 16);
}

// async 16B global -> LDS (wave-uniform LDS base; HW adds lane*16)
DEV void glds16(const void* g, void* l) {
  __builtin_amdgcn_global_load_lds(
      (const __attribute__((address_space(1))) void*)g,
      (__attribute__((address_space(3))) void*)l, 16, 0, 0);
}

constexpr int NROW = 12288;

// ---------------- P0: t0T = (x @ W0)^T  -> bf16 [128][12288] ----------------
__global__ __launch_bounds__(256) void xw_kernel(
    const float* __restrict__ x, const float* __restrict__ W0,
    unsigned short* __restrict__ t0T) {
  __shared__ float sW[128 * 128];
  __shared__ float sx[16][128];
  const int t = threadIdx.x;
  for (int i = t; i < 128 * 128; i += 256) sW[i] = W0[i];
  const int r0 = blockIdx.x * 16;
  for (int i = t; i < 16 * 128; i += 256)
    sx[i >> 7][i & 127] = x[(size_t)(r0 + (i >> 7)) * 128 + (i & 127)];
  __syncthreads();
  const int c = t & 127;   // output column 0..127
  const int rg = t >> 7;   // row group: rows rg*8 .. rg*8+7
  float acc[8] = {0, 0, 0, 0, 0, 0, 0, 0};
  for (int k = 0; k < 128; ++k) {
    float w = sW[k * 128 + c];
#pragma unroll
    for (int j = 0; j < 8; ++j) acc[j] += sx[rg * 8 + j][k] * w;
  }
  uint4 o;
  o.x = pk2(acc[0], acc[1]);
  o.y = pk2(acc[2], acc[3]);
  o.z = pk2(acc[4], acc[5]);
  o.w = pk2(acc[6], acc[7]);
  *(uint4*)(t0T + (size_t)c * NROW + r0 + rg * 8) = o;
}

// ------------- big GEMM: part[split] = adj_chunk @ t   (bf16 MFMA) -----------
// A: [12288][12288] f32 (adj), BT: [H][12288] bf16 (t transposed)
// part: [KSPLIT][12288][H] f32
// Structure = R6 (best: superstep A bursts, B global_load_lds double-buffer,
// raw s_barrier + counted vmcnt, XOR-swizzled LDS, split-per-XCD remap).
// ONE change: A-load lane remap for per-instruction coalescing. Old pattern
// put the 4 q-lanes of a row at 64B stride (64x16B requests/instr, no
// merging). New pattern: load (j,i) reads j*256 + i*64 + q*16 bytes of the
// row -> q-lanes cover one contiguous 64B segment (4:1 request merge).
// LDS slice-write becomes 4x uint2 at (r*128 + i*32 + q*8)^sw (same bytes,
// swizzle XOR only touches bits>=16 -> 8B pieces stay in-cell; 2-way banks).
template <int H>
__global__ __launch_bounds__(256, 3) void gcn_gemm(
    const float* __restrict__ A, const unsigned short* __restrict__ BT,
    float* __restrict__ part) {
  constexpr int KSPLIT = 4;
  constexpr int BM = 64, BK = 64;
  constexpr int WN = (H >= 64) ? 2 : 1;
  constexpr int WM = 4 / WN;
  constexpr int MR = BM / (WM * 16);
  constexpr int NR = H / (WN * 16);
  constexpr int NB = H / 32;                    // B DMA rounds (per thread)
  constexpr int KSTEPS = (NROW / KSPLIT) / BK;  // 48 = 3*16
  constexpr int NSUP = KSTEPS / 3;              // 16 supersteps
  constexpr int BBYTES = H * 128;               // one B^T tile (bf16)
  static_assert(KSTEPS % 3 == 0, "");

  __shared__ alignas(16) char lds[16384 + 2 * BBYTES];
  char* ldsB = lds + 16384;

  const int t = threadIdx.x;
  // ---- split-per-XCD remap (grid = 768 = 8 XCD * 96) ----
  const int xcd = blockIdx.x & 7;
  const int idx = blockIdx.x >> 3;          // 0..95
  const int split = xcd >> 1;               // one split per XCD
  const int bm = ((xcd & 1) ? 96 : 0) + idx;
  const int k0 = split * (NROW / KSPLIT);

  // ---- A staging: 4 threads/row (r=t>>2, q=t&3). Superstep = 3 steps x
  //      64 floats. Load (j,i): bytes j*256 + i*64 + q*16 of the row ->
  //      per-instruction the 4 q-lanes are CONTIGUOUS 64B (request merge).
  const int r = t >> 2, q = t & 3;
  const float* aptr = A + (size_t)(bm * BM + r) * NROW + k0;
  const int sw = (r & 7) << 4;

  // ---- B^T staging source: swizzle folded into global address ----
  const int nB0 = t >> 3;                    // row within round (+32/round)
  const int wB = (t & 7) ^ (nB0 & 7);        // pre-swizzled 16B chunk in row
  const unsigned short* bptr = BT + (size_t)nB0 * NROW + k0 + wB * 8;
  const int wid = t >> 6;
  char* ldsBw = ldsB + wid * 1024;           // wave-uniform B DMA base

  // ---- MFMA fragment LDS offsets ----
  const int lane = t & 63;
  const int l15 = lane & 15;
  const int loct = lane >> 4;
  const int wm = wid / WN;
  const int wn = wid % WN;
  int aoff[MR][2], boff[NR][2];
#pragma unroll
  for (int m = 0; m < MR; ++m)
#pragma unroll
    for (int kk = 0; kk < 2; ++kk) {
      int row = wm * (MR * 16) + m * 16 + l15;
      aoff[m][kk] = (row * 128 + kk * 64 + loct * 16) ^ ((row & 7) << 4);
    }
#pragma unroll
  for (int n = 0; n < NR; ++n)
#pragma unroll
    for (int kk = 0; kk < 2; ++kk) {
      int nn = wn * (NR * 16) + n * 16 + l15;
      boff[n][kk] = (nn * 128 + kk * 64 + loct * 16) ^ ((nn & 7) << 4);
    }

  f32x4 acc[MR][NR];
#pragma unroll
  for (int m = 0; m < MR; ++m)
#pragma unroll
    for (int n = 0; n < NR; ++n) acc[m][n] = {0.f, 0.f, 0.f, 0.f};

  f32x4 av[12];   // one superstep's A (48 VGPR); av[j*4+i]

  auto issueSuper = [&](int S) {
#pragma unroll
    for (int j = 0; j < 3; ++j)
#pragma unroll
      for (int i = 0; i < 4; ++i)
        av[j * 4 + i] =
            *(const f32x4*)(aptr + S * 192 + j * 64 + i * 16 + q * 4);
  };
  auto glB = [&](int s, int buf) {
#pragma unroll
    for (int j = 0; j < NB; ++j)
      glds16(bptr + (size_t)j * 32 * NROW + s * BK,
             ldsBw + buf * BBYTES + j * 4096);
  };
  auto cvtWrite = [&](int j, int buf) {   // write slice j into A buf
    char* wb = lds + buf * 8192;
#pragma unroll
    for (int i = 0; i < 4; ++i) {
      uint2 w;
      w.x = pk2(av[j * 4 + i].x, av[j * 4 + i].y);
      w.y = pk2(av[j * 4 + i].z, av[j * 4 + i].w);
      *(uint2*)(wb + ((r * 128 + i * 32 + q * 8) ^ sw)) = w;
    }
  };
  auto compute = [&](int buf) {
    const char* lA = lds + buf * 8192;
    const char* lB = ldsB + buf * BBYTES;
#pragma unroll
    for (int kk = 0; kk < 2; ++kk) {
      short8 af[MR], bfv[NR];
#pragma unroll
      for (int m = 0; m < MR; ++m) af[m] = *(const short8*)(lA + aoff[m][kk]);
#pragma unroll
      for (int n = 0; n < NR; ++n) bfv[n] = *(const short8*)(lB + boff[n][kk]);
#pragma unroll
      for (int m = 0; m < MR; ++m)
#pragma unroll
        for (int n = 0; n < NR; ++n)
          acc[m][n] = __builtin_amdgcn_mfma_f32_16x16x32_bf16(
              af[m], bfv[n], acc[m][n], 0, 0, 0);
    }
  };

  // ---- Prologue: set0 burst; B(0) DMA; A slice0 -> buf0 ----
  glB(0, 0);
  __builtin_amdgcn_sched_barrier(0);   // pin: DMAs precede A loads
  issueSuper(0);
  cvtWrite(0, 0);          // compiler waits av arrival
  asm volatile("s_waitcnt vmcnt(0) lgkmcnt(0)" ::: "memory");
  __builtin_amdgcn_s_barrier();
  __builtin_amdgcn_sched_barrier(0);

  for (int S = 0; S < NSUP; ++S) {
    const int b = S & 1;   // parity of step 3S
    // ---- step 3S: stage (3S+1) ----
    glB(3 * S + 1, b ^ 1);
    compute(b);
    cvtWrite(1, b ^ 1);
    asm volatile("s_waitcnt vmcnt(0) lgkmcnt(0)" ::: "memory");
    __builtin_amdgcn_s_barrier();
    __builtin_amdgcn_sched_barrier(0);
    // ---- step 3S+1: stage (3S+2); burst-issue set S+1 ----
    glB(3 * S + 2, b);
    __builtin_amdgcn_sched_barrier(0);   // pin: DMAs before A prefetch
    compute(b ^ 1);
    cvtWrite(2, b);
    if (S + 1 < NSUP) {
      issueSuper(S + 1);   // 12 loads stay in flight across barrier
      asm volatile("s_waitcnt vmcnt(12) lgkmcnt(0)" ::: "memory");
    } else {
      asm volatile("s_waitcnt vmcnt(0) lgkmcnt(0)" ::: "memory");
    }
    __builtin_amdgcn_s_barrier();
    __builtin_amdgcn_sched_barrier(0);
    // ---- step 3S+2: stage (3S+3) from NEW set ----
    if (S + 1 < NSUP) {
      glB(3 * S + 3, b ^ 1);
      compute(b);
      cvtWrite(0, b ^ 1);  // compiler waits new set arrival
      asm volatile("s_waitcnt vmcnt(0) lgkmcnt(0)" ::: "memory");
      __builtin_amdgcn_s_barrier();
      __builtin_amdgcn_sched_barrier(0);
    } else {
      compute(b);          // final step, no staging
    }
  }

  float* pout = part + ((size_t)split * NROW + (size_t)bm * BM) * H;
#pragma unroll
  for (int m = 0; m < MR; ++m) {
    const int row = wm * (MR * 16) + m * 16 + loct * 4;
#pragma unroll
    for (int n = 0; n < NR; ++n) {
      const int col = wn * (NR * 16) + n * 16 + l15;
#pragma unroll
      for (int rr = 0; rr < 4; ++rr)
        pout[(size_t)(row + rr) * H + col] = acc[m][n][rr];
    }
  }
}

// ------- reduce: sum splits + bias + LN + (leaky) + @Wnext -> t_next^T -------
template <int H, int H2, bool ACT>
__global__ __launch_bounds__(256) void reduce_ln(
    const float* __restrict__ part, const float* __restrict__ bias,
    const float* __restrict__ g, const float* __restrict__ be,
    const float* __restrict__ Wn, unsigned short* __restrict__ tT) {
  __shared__ float sW[H * H2];
  __shared__ float sh[4][H];
  const int t = threadIdx.x;
  for (int i = t; i < H * H2; i += 256) sW[i] = Wn[i];
  __syncthreads();

  const int wid = t >> 6, lane = t & 63;
  const int row = blockIdx.x * 4 + wid;
  constexpr int CPL = H / 64;
  float v[CPL];
#pragma unroll
  for (int c = 0; c < CPL; ++c) {
    const int col = lane + c * 64;
    float s = bias[col];
#pragma unroll
    for (int sp = 0; sp < 4; ++sp)
      s += part[((size_t)sp * NROW + row) * H + col];
    v[c] = s;
  }
  float sum = 0;
#pragma unroll
  for (int c = 0; c < CPL; ++c) sum += v[c];
#pragma unroll
  for (int o = 32; o > 0; o >>= 1) sum += __shfl_xor(sum, o);
  const float mu = sum / H;
  float vs = 0;
#pragma unroll
  for (int c = 0; c < CPL; ++c) { float d = v[c] - mu; vs += d * d; }
#pragma unroll
  for (int o = 32; o > 0; o >>= 1) vs += __shfl_xor(vs, o);
  const float rstd = rsqrtf(vs / H + 1e-5f);
#pragma unroll
  for (int c = 0; c < CPL; ++c) {
    const int col = lane + c * 64;
    float h = (v[c] - mu) * rstd * g[col] + be[col];
    if (ACT) h = (h > 0.f) ? h : 0.01f * h;
    sh[wid][col] = h;
  }
  __syncthreads();
  if (lane < H2) {
    float d = 0;
#pragma unroll 8
    for (int k = 0; k < H; ++k) d += sh[wid][k] * sW[k * H2 + lane];
    tT[(size_t)lane * NROW + row] = f2bf(d);
  }
}

// ------- final: sum splits + bias + LN + leaky + @Wl+bl + log_softmax -------
__global__ __launch_bounds__(256) void reduce_final(
    const float* __restrict__ part, const float* __restrict__ bias,
    const float* __restrict__ g, const float* __restrict__ be,
    const float* __restrict__ Wl, const float* __restrict__ bl,
    float* __restrict__ out) {
  __shared__ float sW[32 * 20];
  __shared__ float sbl[20];
  __shared__ float sh[4][32];
  __shared__ float sl[4][20];
  const int t = threadIdx.x;
  for (int i = t; i < 640; i += 256) sW[i] = Wl[i];
  if (t < 20) sbl[t] = bl[t];
  __syncthreads();
  const int wid = t >> 6, lane = t & 63;
  const int row = blockIdx.x * 4 + wid;
  const int col = lane & 31;  // lanes 32..63 duplicate cols 0..31
  float v = bias[col];
#pragma unroll
  for (int sp = 0; sp < 4; ++sp)
    v += part[((size_t)sp * NROW + row) * 32 + col];
  float sum = v;
#pragma unroll
  for (int o = 32; o > 0; o >>= 1) sum += __shfl_xor(sum, o);
  const float mu = sum / 64.f;  // values duplicated 2x across the wave
  float d0 = v - mu;
  float vs = d0 * d0;
#pragma unroll
  for (int o = 32; o > 0; o >>= 1) vs += __shfl_xor(vs, o);
  const float rstd = rsqrtf(vs / 64.f + 1e-5f);
  float h = (v - mu) * rstd * g[col] + be[col];
  h = (h > 0.f) ? h : 0.01f * h;
  if (lane < 32) sh[wid][col] = h;
  __syncthreads();
  if (lane < 20) {
    float lg = sbl[lane];
#pragma unroll
    for (int k = 0; k < 32; ++k) lg += sh[wid][k] * sW[k * 20 + lane];
    sl[wid][lane] = lg;
  }
  __syncthreads();
  if (lane < 20) {
    float mx = -1e30f;
#pragma unroll
    for (int k = 0; k < 20; ++k) mx = fmaxf(mx, sl[wid][k]);
    float se = 0.f;
#pragma unroll
    for (int k = 0; k < 20; ++k) se += expf(sl[wid][k] - mx);
    out[(size_t)row * 20 + lane] = sl[wid][lane] - mx - logf(se);
  }
}

extern "C" void kernel_launch(void* const* d_in, const int* in_sizes, int n_in,
                              void* d_out, int out_size, void* d_ws,
                              size_t ws_size, hipStream_t stream) {
  const float* x    = (const float*)d_in[0];
  const float* adj0 = (const float*)d_in[1];
  const float* adj1 = (const float*)d_in[2];
  const float* adj2 = (const float*)d_in[3];
  const float* W0   = (const float*)d_in[4];
  const float* b0   = (const float*)d_in[5];
  const float* W1   = (const float*)d_in[6];
  const float* b1   = (const float*)d_in[7];
  const float* W2   = (const float*)d_in[8];
  const float* b2   = (const float*)d_in[9];
  const float* g0   = (const float*)d_in[10];
  const float* be0  = (const float*)d_in[11];
  const float* g1   = (const float*)d_in[12];
  const float* be1  = (const float*)d_in[13];
  const float* g2   = (const float*)d_in[14];
  const float* be2  = (const float*)d_in[15];
  const float* Wl   = (const float*)d_in[16];
  const float* bl   = (const float*)d_in[17];
  float* out = (float*)d_out;

  char* ws = (char*)d_ws;
  float* part =          (float*)(ws);                      // 4*12288*128*4 = 25165824 B
  unsigned short* t0T = (unsigned short*)(ws + 25165824);   // 128*12288*2 = 3145728 B
  unsigned short* t1T = (unsigned short*)(ws + 25165824 + 3145728);          // 1572864 B
  unsigned short* t2T = (unsigned short*)(ws + 25165824 + 3145728 + 1572864); // 786432 B

  xw_kernel<<<NROW / 16, 256, 0, stream>>>(x, W0, t0T);
  gcn_gemm<128><<<(NROW / 64) * 4, 256, 0, stream>>>(adj0, t0T, part);
  reduce_ln<128, 64, false><<<NROW / 4, 256, 0, stream>>>(part, b0, g0, be0, W1, t1T);
  gcn_gemm<64><<<(NROW / 64) * 4, 256, 0, stream>>>(adj1, t1T, part);
  reduce_ln<64, 32, true><<<NROW / 4, 256, 0, stream>>>(part, b1, g1, be1, W2, t2T);
  gcn_gemm<32><<<(NROW / 64) * 4, 256, 0, stream>>>(adj2, t2T, part);
  reduce_final<<<NROW / 4, 256, 0, stream>>>(part, b2, g2, be2, Wl, bl, out);
}